// Round 12
// baseline (702.433 us; speedup 1.0000x reference)
//
#include <hip/hip_runtime.h>

typedef unsigned int uint;
typedef unsigned short ushort;
typedef _Float16 f16_t;
typedef f16_t f16x8 __attribute__((ext_vector_type(8)));
typedef ushort ushort8 __attribute__((ext_vector_type(8)));
typedef float f32x4 __attribute__((ext_vector_type(4)));

#define NN 200000
#define EE 600000
#define LL 5
#define GG 2000
#define SCAN_NB 782  // ceil(NN/256)

__device__ __forceinline__ ushort f2h(float f) {
  f16_t h = (f16_t)f;
  return __builtin_bit_cast(ushort, h);
}
__device__ __forceinline__ float h2f(ushort u) {
  return (float)__builtin_bit_cast(f16_t, u);
}
__device__ __forceinline__ float hlo(uint u) { return h2f((ushort)(u & 0xFFFFu)); }
__device__ __forceinline__ float hhi(uint u) { return h2f((ushort)(u >> 16)); }

// ---------------- merged setup: weight swizzle + tables + xcode + outinit ----------
__global__ void k_setup(const float* __restrict__ W1, const float* __restrict__ W2,
                        ushort* __restrict__ w1s, ushort* __restrict__ w2s,
                        const float* __restrict__ ee1, const float* __restrict__ ee2,
                        const float* __restrict__ at1, const float* __restrict__ at2,
                        float* __restrict__ tab, const int* __restrict__ xidx,
                        int* __restrict__ xcode, float* __restrict__ out,
                        const float* __restrict__ bp) {
  int i = blockIdx.x * 256 + threadIdx.x;
  if (i < 40960) {  // weight swizzle, B-frag 16x16x32 order
    int lane = i & 63;
    int f = i >> 6;
    bool isW2 = false;
    if (f >= 320) { f -= 320; isW2 = true; }
    int l = f >> 6, rem = f & 63;
    ushort8 o;
    if (!isW2) {
      int kt = rem >> 4, nt = rem & 15;
      int n = nt * 16 + (lane & 15);
      int kbase = kt * 32 + (lane >> 4) * 8;
#pragma unroll
      for (int j = 0; j < 8; ++j) o[j] = f2h(W1[l * 32768 + (kbase + j) * 256 + n]);
      *(ushort8*)(w1s + f * 512 + lane * 8) = o;
    } else {
      int kt = rem >> 3, nt = rem & 7;
      int n = nt * 16 + (lane & 15);
      int kbase = kt * 32 + (lane >> 4) * 8;
#pragma unroll
      for (int j = 0; j < 8; ++j) o[j] = f2h(W2[l * 32768 + (kbase + j) * 128 + n]);
      *(ushort8*)(w2s + f * 512 + lane * 8) = o;
    }
  }
  if (i < 5760) {  // comb
    int l = i / 1152, rem = i % 1152;
    int ab = rem >> 7, c = rem & 127;
    int a = ab / 3, b = ab - a * 3;
    tab[i] = ee1[(l * 6 + a) * 128 + c] + ee2[(l * 3 + b) * 128 + c];
  } else if (i < 6400) {  // selfv
    int j = i - 5760;
    int l = j >> 7, c = j & 127;
    tab[i] = ee1[(l * 6 + 4) * 128 + c] + ee2[(l * 3 + 0) * 128 + c];
  } else if (i < 7552) {  // atomc
    int j = i - 6400;
    int ab = j >> 7, c = j & 127;
    int a = ab / 3, b = ab - a * 3;
    tab[i] = at1[a * 128 + c] + at2[b * 128 + c];
  }
  if (i < NN) xcode[i] = xidx[2 * i] * 3 + xidx[2 * i + 1];
  if (i < GG) out[i] = bp[0];
}

// ---------------- CSR build (dst is fixed across layers) ----------------
__global__ void k_count(const int* __restrict__ ei, int* __restrict__ counts) {
  int e = blockIdx.x * 256 + threadIdx.x;
  if (e < EE) atomicAdd(&counts[ei[EE + e]], 1);
}

__global__ void k_scanA(const int* __restrict__ counts, int* __restrict__ rowptr,
                        int* __restrict__ bsums) {
  __shared__ int sd[256];
  int tid = threadIdx.x;
  int g = blockIdx.x * 256 + tid;
  int v = (g < NN) ? counts[g] : 0;
  sd[tid] = v;
  __syncthreads();
  for (int o = 1; o < 256; o <<= 1) {
    int t = (tid >= o) ? sd[tid - o] : 0;
    __syncthreads();
    sd[tid] += t;
    __syncthreads();
  }
  if (g < NN) rowptr[g] = sd[tid] - v;
  if (tid == 255) bsums[blockIdx.x] = sd[tid];
}

__global__ void k_scanB(int* __restrict__ bsums) {
  __shared__ int sd[1024];
  int tid = threadIdx.x;
  int v = (tid < SCAN_NB) ? bsums[tid] : 0;
  sd[tid] = v;
  __syncthreads();
  for (int o = 1; o < 1024; o <<= 1) {
    int t = (tid >= o) ? sd[tid - o] : 0;
    __syncthreads();
    sd[tid] += t;
    __syncthreads();
  }
  if (tid < SCAN_NB) bsums[tid] = sd[tid] - v;
}

__global__ void k_scanC(int* __restrict__ rowptr, const int* __restrict__ bsums) {
  int g = blockIdx.x * 256 + threadIdx.x;
  if (g < NN) rowptr[g] += bsums[blockIdx.x];
  if (g == 0) rowptr[NN] = EE;
}

// pack src (18b) | a9 (4b) | xcode_src (4b)
__global__ void k_fill(const int* __restrict__ ei, const int* __restrict__ ea,
                       const int* __restrict__ xcode, int* __restrict__ cursor,
                       int* __restrict__ eslot) {
  int e = blockIdx.x * 256 + threadIdx.x;
  if (e < EE) {
    int dst = ei[EE + e];
    int src = ei[e];
    int a9 = ea[2 * e] * 3 + ea[2 * e + 1];
    int sc = xcode[src];
    int pos = atomicAdd(&cursor[dst], 1);
    eslot[pos] = src | (a9 << 18) | (sc << 22);
  }
}

// ---------------- gather: message passing, writes agg (fp16) to global ----------
// Split from the MLP so the latency-bound phase carries NO MFMA accumulators
// (unified VGPR+AGPR file: fused kernel's ~104+ total regs capped residency at
// 4 waves/SIMD = 50%). No LDS, no barriers; ~90 regs -> 5-6 waves/SIMD.
// Block = 256 thr = 4 waves; 32 nodes/block; 16-lane sub-group per node; x2 unroll.
__global__ __launch_bounds__(256, 4) void k_gather(
    const ushort* __restrict__ zin, ushort* __restrict__ agg,
    const int* __restrict__ xcode, const float* __restrict__ tab,
    const float* __restrict__ bnscale, const float* __restrict__ bnshift,
    const int* __restrict__ rowptr, const int* __restrict__ eslot, int layer) {
  const int tid = threadIdx.x;
  const int w = tid >> 6, lane = tid & 63;
  const int ln16 = lane & 15, sub = lane >> 4;
  const int row0 = blockIdx.x * 32;

  const float4* combL4 = (const float4*)(tab + (size_t)layer * 1152);
  const float4* at4 = (const float4*)(tab + 6400);
  const float4* sfp = (const float4*)(tab + 5760 + layer * 128);
  float4 sf0 = sfp[ln16 * 2], sf1 = sfp[ln16 * 2 + 1];
  float4 scv0 = {}, scv1 = {}, shv0 = {}, shv1 = {};
  if (layer > 0) {
    const float4* scp = (const float4*)(bnscale + (layer - 1) * 128);
    const float4* shp = (const float4*)(bnshift + (layer - 1) * 128);
    scv0 = scp[ln16 * 2];
    scv1 = scp[ln16 * 2 + 1];
    shv0 = shp[ln16 * 2];
    shv1 = shp[ln16 * 2 + 1];
  }
  const uint4* z4 = (const uint4*)zin;

#pragma unroll
  for (int grp = 0; grp < 2; ++grp) {
    const int n = row0 + w * 8 + grp * 4 + sub;
    const int s = rowptr[n], e = rowptr[n + 1];
    float a[8];
    if (layer == 0) {
      int code = xcode[n];
      float4 h0 = at4[code * 32 + ln16 * 2], h1 = at4[code * 32 + ln16 * 2 + 1];
      a[0] = h0.x + sf0.x; a[1] = h0.y + sf0.y; a[2] = h0.z + sf0.z; a[3] = h0.w + sf0.w;
      a[4] = h1.x + sf1.x; a[5] = h1.y + sf1.y; a[6] = h1.z + sf1.z; a[7] = h1.w + sf1.w;
    } else {
      uint4 su = z4[(size_t)n * 16 + ln16];
      a[0] = fmaxf(fmaf(hlo(su.x), scv0.x, shv0.x), 0.f) + sf0.x;
      a[1] = fmaxf(fmaf(hhi(su.x), scv0.y, shv0.y), 0.f) + sf0.y;
      a[2] = fmaxf(fmaf(hlo(su.y), scv0.z, shv0.z), 0.f) + sf0.z;
      a[3] = fmaxf(fmaf(hhi(su.y), scv0.w, shv0.w), 0.f) + sf0.w;
      a[4] = fmaxf(fmaf(hlo(su.z), scv1.x, shv1.x), 0.f) + sf1.x;
      a[5] = fmaxf(fmaf(hhi(su.z), scv1.y, shv1.y), 0.f) + sf1.y;
      a[6] = fmaxf(fmaf(hlo(su.w), scv1.z, shv1.z), 0.f) + sf1.z;
      a[7] = fmaxf(fmaf(hhi(su.w), scv1.w, shv1.w), 0.f) + sf1.w;
    }
    for (int base = s; base < e; base += 16) {
      int m = e - base;
      if (m > 16) m = 16;
      int slot = (ln16 < m) ? eslot[base + ln16] : 0;
      int j = 0;
      for (; j + 2 <= m; j += 2) {
        int sl0 = __shfl(slot, sub * 16 + j, 64);
        int sl1 = __shfl(slot, sub * 16 + j + 1, 64);
        int a9_0 = (sl0 >> 18) & 15, a9_1 = (sl1 >> 18) & 15;
        float4 p0, p1, q0, q1;
        if (layer == 0) {
          int c0 = (sl0 >> 22) & 15, c1 = (sl1 >> 22) & 15;
          p0 = at4[c0 * 32 + ln16 * 2]; p1 = at4[c0 * 32 + ln16 * 2 + 1];
          q0 = at4[c1 * 32 + ln16 * 2]; q1 = at4[c1 * 32 + ln16 * 2 + 1];
        } else {
          int s0 = sl0 & 0x3FFFF, s1 = sl1 & 0x3FFFF;
          uint4 u0 = z4[(size_t)s0 * 16 + ln16];
          uint4 u1 = z4[(size_t)s1 * 16 + ln16];
          p0.x = fmaxf(fmaf(hlo(u0.x), scv0.x, shv0.x), 0.f);
          p0.y = fmaxf(fmaf(hhi(u0.x), scv0.y, shv0.y), 0.f);
          p0.z = fmaxf(fmaf(hlo(u0.y), scv0.z, shv0.z), 0.f);
          p0.w = fmaxf(fmaf(hhi(u0.y), scv0.w, shv0.w), 0.f);
          p1.x = fmaxf(fmaf(hlo(u0.z), scv1.x, shv1.x), 0.f);
          p1.y = fmaxf(fmaf(hhi(u0.z), scv1.y, shv1.y), 0.f);
          p1.z = fmaxf(fmaf(hlo(u0.w), scv1.z, shv1.z), 0.f);
          p1.w = fmaxf(fmaf(hhi(u0.w), scv1.w, shv1.w), 0.f);
          q0.x = fmaxf(fmaf(hlo(u1.x), scv0.x, shv0.x), 0.f);
          q0.y = fmaxf(fmaf(hhi(u1.x), scv0.y, shv0.y), 0.f);
          q0.z = fmaxf(fmaf(hlo(u1.y), scv0.z, shv0.z), 0.f);
          q0.w = fmaxf(fmaf(hhi(u1.y), scv0.w, shv0.w), 0.f);
          q1.x = fmaxf(fmaf(hlo(u1.z), scv1.x, shv1.x), 0.f);
          q1.y = fmaxf(fmaf(hhi(u1.z), scv1.y, shv1.y), 0.f);
          q1.z = fmaxf(fmaf(hlo(u1.w), scv1.z, shv1.z), 0.f);
          q1.w = fmaxf(fmaf(hhi(u1.w), scv1.w, shv1.w), 0.f);
        }
        float4 cb00 = combL4[a9_0 * 32 + ln16 * 2], cb01 = combL4[a9_0 * 32 + ln16 * 2 + 1];
        float4 cb10 = combL4[a9_1 * 32 + ln16 * 2], cb11 = combL4[a9_1 * 32 + ln16 * 2 + 1];
        a[0] += p0.x + cb00.x; a[1] += p0.y + cb00.y;
        a[2] += p0.z + cb00.z; a[3] += p0.w + cb00.w;
        a[4] += p1.x + cb01.x; a[5] += p1.y + cb01.y;
        a[6] += p1.z + cb01.z; a[7] += p1.w + cb01.w;
        a[0] += q0.x + cb10.x; a[1] += q0.y + cb10.y;
        a[2] += q0.z + cb10.z; a[3] += q0.w + cb10.w;
        a[4] += q1.x + cb11.x; a[5] += q1.y + cb11.y;
        a[6] += q1.z + cb11.z; a[7] += q1.w + cb11.w;
      }
      if (j < m) {
        int sl = __shfl(slot, sub * 16 + j, 64);
        int a9 = (sl >> 18) & 15;
        float4 cb0 = combL4[a9 * 32 + ln16 * 2], cb1 = combL4[a9 * 32 + ln16 * 2 + 1];
        if (layer == 0) {
          int scode = (sl >> 22) & 15;
          float4 h0 = at4[scode * 32 + ln16 * 2], h1 = at4[scode * 32 + ln16 * 2 + 1];
          a[0] += h0.x + cb0.x; a[1] += h0.y + cb0.y;
          a[2] += h0.z + cb0.z; a[3] += h0.w + cb0.w;
          a[4] += h1.x + cb1.x; a[5] += h1.y + cb1.y;
          a[6] += h1.z + cb1.z; a[7] += h1.w + cb1.w;
        } else {
          int src = sl & 0x3FFFF;
          uint4 u = z4[(size_t)src * 16 + ln16];
          a[0] += fmaxf(fmaf(hlo(u.x), scv0.x, shv0.x), 0.f) + cb0.x;
          a[1] += fmaxf(fmaf(hhi(u.x), scv0.y, shv0.y), 0.f) + cb0.y;
          a[2] += fmaxf(fmaf(hlo(u.y), scv0.z, shv0.z), 0.f) + cb0.z;
          a[3] += fmaxf(fmaf(hhi(u.y), scv0.w, shv0.w), 0.f) + cb0.w;
          a[4] += fmaxf(fmaf(hlo(u.z), scv1.x, shv1.x), 0.f) + cb1.x;
          a[5] += fmaxf(fmaf(hhi(u.z), scv1.y, shv1.y), 0.f) + cb1.y;
          a[6] += fmaxf(fmaf(hlo(u.w), scv1.z, shv1.z), 0.f) + cb1.z;
          a[7] += fmaxf(fmaf(hhi(u.w), scv1.w, shv1.w), 0.f) + cb1.w;
        }
      }
    }
    uint o0 = (uint)f2h(a[0]) | ((uint)f2h(a[1]) << 16);
    uint o1 = (uint)f2h(a[2]) | ((uint)f2h(a[3]) << 16);
    uint o2 = (uint)f2h(a[4]) | ((uint)f2h(a[5]) << 16);
    uint o3 = (uint)f2h(a[6]) | ((uint)f2h(a[7]) << 16);
    uint4 ov = {o0, o1, o2, o3};
    ((uint4*)agg)[(size_t)n * 16 + ln16] = ov;
  }
}

// ---------------- MLP: z = relu(agg@W1+b1)@W2+b2, in-place on buf, M=64 ----------
// r2's proven in-place structure: block reads ONLY its own 64 agg rows (global,
// L2/L3-hot from k_gather) then overwrites them with z -> agg shares the ping-pong
// buffer, no extra ws. Compute-dense: AGPR pressure is fine here.
__global__ __launch_bounds__(256, 3) void k_mlp(ushort* __restrict__ buf,
                                                const ushort* __restrict__ w1s,
                                                const ushort* __restrict__ w2s,
                                                const float* __restrict__ b1,
                                                const float* __restrict__ b2,
                                                float* __restrict__ stats, int layer) {
  __shared__ __align__(16) ushort T1[64 * 264];  // 33,792 B; ldsZ (64x136) aliases
  ushort* ldsZ = T1;
  const int tid = threadIdx.x;
  const int w = tid >> 6, lane = tid & 63;
  const int lm = lane & 15, q = lane >> 4;
  const int row0 = blockIdx.x * 64;

  // ---- stage 1: T1 = relu(agg @ W1 + b1) ----
  f32x4 acc[4][4] = {};
  const ushort* w1b = w1s + layer * 64 * 512;
#pragma unroll
  for (int kt = 0; kt < 4; ++kt) {
    f16x8 af[4], bf[4];
#pragma unroll
    for (int mt = 0; mt < 4; ++mt) {
      const ushort* p = buf + (size_t)(row0 + mt * 16 + lm) * 128 + kt * 32 + q * 8;
      af[mt] = __builtin_bit_cast(f16x8, *(const ushort8*)p);
    }
#pragma unroll
    for (int nt = 0; nt < 4; ++nt) {
      const ushort* p = w1b + (kt * 16 + w * 4 + nt) * 512 + lane * 8;
      bf[nt] = __builtin_bit_cast(f16x8, *(const ushort8*)p);
    }
#pragma unroll
    for (int mt = 0; mt < 4; ++mt)
#pragma unroll
      for (int nt = 0; nt < 4; ++nt)
        acc[mt][nt] = __builtin_amdgcn_mfma_f32_16x16x32_f16(af[mt], bf[nt], acc[mt][nt], 0, 0, 0);
  }
#pragma unroll
  for (int nt = 0; nt < 4; ++nt) {
    int n = w * 64 + nt * 16 + lm;
    float bias = b1[layer * 256 + n];
#pragma unroll
    for (int mt = 0; mt < 4; ++mt)
#pragma unroll
      for (int r = 0; r < 4; ++r) {
        float v = fmaxf(acc[mt][nt][r] + bias, 0.0f);
        T1[(mt * 16 + q * 4 + r) * 264 + n] = f2h(v);
      }
  }
  __syncthreads();

  // ---- stage 2: z = T1 @ W2 + b2, + BN stats epilogue ----
  f32x4 acc2[4][2] = {};
  const ushort* w2b = w2s + layer * 64 * 512;
#pragma unroll
  for (int kt = 0; kt < 8; ++kt) {
    f16x8 af[4], bf[2];
#pragma unroll
    for (int mt = 0; mt < 4; ++mt) {
      const ushort* p = T1 + (mt * 16 + lm) * 264 + kt * 32 + q * 8;
      af[mt] = __builtin_bit_cast(f16x8, *(const ushort8*)p);
    }
#pragma unroll
    for (int nt = 0; nt < 2; ++nt) {
      const ushort* p = w2b + (kt * 8 + w * 2 + nt) * 512 + lane * 8;
      bf[nt] = __builtin_bit_cast(f16x8, *(const ushort8*)p);
    }
#pragma unroll
    for (int mt = 0; mt < 4; ++mt)
#pragma unroll
      for (int nt = 0; nt < 2; ++nt)
        acc2[mt][nt] = __builtin_amdgcn_mfma_f32_16x16x32_f16(af[mt], bf[nt], acc2[mt][nt], 0, 0, 0);
  }
  __syncthreads();  // T1 dead; ldsZ may overwrite
  float ssum[2], ssq[2];
#pragma unroll
  for (int nt = 0; nt < 2; ++nt) {
    int n = w * 32 + nt * 16 + lm;
    float bias = b2[layer * 128 + n];
    ssum[nt] = 0.f;
    ssq[nt] = 0.f;
#pragma unroll
    for (int mt = 0; mt < 4; ++mt)
#pragma unroll
      for (int r = 0; r < 4; ++r) {
        float v = acc2[mt][nt][r] + bias;
        ldsZ[(mt * 16 + q * 4 + r) * 136 + n] = f2h(v);
        ssum[nt] += v;
        ssq[nt] += v * v;
      }
    ssum[nt] += __shfl_xor(ssum[nt], 16, 64);
    ssum[nt] += __shfl_xor(ssum[nt], 32, 64);
    ssq[nt] += __shfl_xor(ssq[nt], 16, 64);
    ssq[nt] += __shfl_xor(ssq[nt], 32, 64);
  }
  if (lane < 16) {
    int cp = blockIdx.x & 15;
    float* sb = stats + (size_t)(layer * 16 + cp) * 256;
#pragma unroll
    for (int nt = 0; nt < 2; ++nt) {
      int col = w * 32 + nt * 16 + lane;
      atomicAdd(&sb[col], ssum[nt]);
      atomicAdd(&sb[128 + col], ssq[nt]);
    }
  }
  __syncthreads();
  uint* zo = (uint*)buf;
  for (int i = tid; i < 64 * 64; i += 256) {
    int row = i >> 6, cpx = i & 63;
    uint v = *(const uint*)&ldsZ[row * 136 + cpx * 2];
    zo[(size_t)(row0 + row) * 64 + cpx] = v;
  }
}

__global__ void k_bnparam(const float* __restrict__ stats, const float* __restrict__ gamma,
                          const float* __restrict__ beta, float* __restrict__ bnscale,
                          float* __restrict__ bnshift, int layer) {
  int c = threadIdx.x;
  float s = 0.f, qv = 0.f;
  for (int cp = 0; cp < 16; ++cp) {
    const float* sb = stats + (size_t)(layer * 16 + cp) * 256;
    s += sb[c];
    qv += sb[128 + c];
  }
  float mu = s * (1.0f / NN);
  float var = qv * (1.0f / NN) - mu * mu;
  float sc = gamma[layer * 128 + c] * rsqrtf(var + 1e-5f);
  bnscale[layer * 128 + c] = sc;
  bnshift[layer * 128 + c] = beta[layer * 128 + c] - mu * sc;
}

// ---------------- pooling with segmented running sum (batch sorted) ----------------
__global__ __launch_bounds__(256) void k_pool(const ushort* __restrict__ z,
                                              const float* __restrict__ bnscale,
                                              const float* __restrict__ bnshift,
                                              const int* __restrict__ batch,
                                              const float* __restrict__ Wp,
                                              float* __restrict__ out) {
  const int tid = threadIdx.x;
  const int w = tid >> 6, lane = tid & 63;
  const int nb = blockIdx.x * 64 + w * 16;
  float2 wp = ((const float2*)Wp)[lane];
  float2 scv = ((const float2*)(bnscale + 4 * 128))[lane];
  float2 shv = ((const float2*)(bnshift + 4 * 128))[lane];
  const uint* z32 = (const uint*)z;
  int bb = (lane < 16) ? batch[nb + lane] : 0;
  int curb = __shfl(bb, 0);
  float run = 0.f;
#pragma unroll
  for (int i = 0; i < 16; ++i) {
    int b = __shfl(bb, i);
    uint u = z32[(size_t)(nb + i) * 64 + lane];
    float dot = fmaf(hlo(u), scv.x, shv.x) * wp.x + fmaf(hhi(u), scv.y, shv.y) * wp.y;
#pragma unroll
    for (int off = 32; off > 0; off >>= 1) dot += __shfl_xor(dot, off, 64);
    if (b != curb) {
      if (lane == 0) atomicAdd(&out[curb], run);
      run = 0.f;
      curb = b;
    }
    run += dot;
  }
  if (lane == 0) atomicAdd(&out[curb], run);
}

extern "C" void kernel_launch(void* const* d_in, const int* in_sizes, int n_in,
                              void* d_out, int out_size, void* d_ws, size_t ws_size,
                              hipStream_t stream) {
  (void)in_sizes; (void)n_in; (void)out_size; (void)ws_size;
  const int* xidx = (const int*)d_in[0];
  const int* eidx = (const int*)d_in[1];
  const int* eattr = (const int*)d_in[2];
  const int* batch = (const int*)d_in[3];
  const float* at1 = (const float*)d_in[4];
  const float* at2 = (const float*)d_in[5];
  const float* ee1 = (const float*)d_in[6];
  const float* ee2 = (const float*)d_in[7];
  const float* W1 = (const float*)d_in[8];
  const float* b1 = (const float*)d_in[9];
  const float* W2 = (const float*)d_in[10];
  const float* b2 = (const float*)d_in[11];
  const float* gamma = (const float*)d_in[12];
  const float* beta = (const float*)d_in[13];
  const float* Wp = (const float*)d_in[14];
  const float* bp = (const float*)d_in[15];
  float* out = (float*)d_out;

  char* ws = (char*)d_ws;
  size_t off = 0;
  auto alloc = [&](size_t bytes) -> void* {
    void* p = ws + off;
    off = (off + bytes + 255) & ~(size_t)255;
    return p;
  };
  ushort* bufA = (ushort*)alloc((size_t)NN * 128 * 2);
  ushort* bufB = (ushort*)alloc((size_t)NN * 128 * 2);
  ushort* w1s = (ushort*)alloc(320 * 512 * 2);
  ushort* w2s = (ushort*)alloc(320 * 512 * 2);
  int* rowptr = (int*)alloc((NN + 1) * 4);
  int* cursor = (int*)alloc((size_t)NN * 4);
  int* eslot = (int*)alloc((size_t)EE * 4);
  int* bsums = (int*)alloc(1024 * 4);
  float* tab = (float*)alloc(7552 * 4);
  int* xcode = (int*)alloc((size_t)NN * 4);
  float* stats = (float*)alloc((size_t)LL * 16 * 256 * 4);
  float* bnscale = (float*)alloc(LL * 128 * 4);
  float* bnshift = (float*)alloc(LL * 128 * 4);

  hipMemsetAsync(cursor, 0, (size_t)NN * 4, stream);
  hipMemsetAsync(stats, 0, (size_t)LL * 16 * 256 * 4, stream);
  k_setup<<<SCAN_NB, 256, 0, stream>>>(W1, W2, w1s, w2s, ee1, ee2, at1, at2, tab, xidx,
                                       xcode, out, bp);
  k_count<<<(EE + 255) / 256, 256, 0, stream>>>(eidx, cursor);
  k_scanA<<<SCAN_NB, 256, 0, stream>>>(cursor, rowptr, bsums);
  k_scanB<<<1, 1024, 0, stream>>>(bsums);
  k_scanC<<<SCAN_NB, 256, 0, stream>>>(rowptr, bsums);
  hipMemcpyAsync(cursor, rowptr, (size_t)NN * 4, hipMemcpyDeviceToDevice, stream);
  k_fill<<<(EE + 255) / 256, 256, 0, stream>>>(eidx, eattr, xcode, cursor, eslot);

  for (int l = 0; l < LL; ++l) {
    ushort* zo = (l & 1) ? bufB : bufA;   // agg + z output (in-place in k_mlp)
    const ushort* zi = (l & 1) ? bufA : bufB;  // z_{l-1}; unused for l==0
    k_gather<<<NN / 32, 256, 0, stream>>>((l == 0) ? bufA : zi, zo, xcode, tab, bnscale,
                                          bnshift, rowptr, eslot, l);
    k_mlp<<<NN / 64, 256, 0, stream>>>(zo, w1s, w2s, b1, b2, stats, l);
    k_bnparam<<<1, 128, 0, stream>>>(stats, gamma, beta, bnscale, bnshift, l);
  }
  k_pool<<<NN / 64, 256, 0, stream>>>(bufA, bnscale, bnshift, batch, Wp, out);
}

// Round 13
// 610.579 us; speedup vs baseline: 1.1504x; 1.1504x over previous
//
#include <hip/hip_runtime.h>

typedef unsigned int uint;
typedef unsigned short ushort;
typedef _Float16 f16_t;
typedef f16_t f16x8 __attribute__((ext_vector_type(8)));
typedef ushort ushort8 __attribute__((ext_vector_type(8)));
typedef float f32x4 __attribute__((ext_vector_type(4)));

#define NN 200000
#define EE 600000
#define LL 5
#define GG 2000
#define SCAN_NB 782  // ceil(NN/256)

__device__ __forceinline__ ushort f2h(float f) {
  f16_t h = (f16_t)f;
  return __builtin_bit_cast(ushort, h);
}
__device__ __forceinline__ float h2f(ushort u) {
  return (float)__builtin_bit_cast(f16_t, u);
}
__device__ __forceinline__ float hlo(uint u) { return h2f((ushort)(u & 0xFFFFu)); }
__device__ __forceinline__ float hhi(uint u) { return h2f((ushort)(u >> 16)); }
__device__ __forceinline__ f16x8 ld8h(const uint4* p, int idx) {
  uint4 u = p[idx];
  return __builtin_bit_cast(f16x8, u);
}

// ---------------- merged setup: weight swizzle + fp16 tables + xcode + outinit ------
__global__ void k_setup(const float* __restrict__ W1, const float* __restrict__ W2,
                        ushort* __restrict__ w1s, ushort* __restrict__ w2s,
                        const float* __restrict__ ee1, const float* __restrict__ ee2,
                        const float* __restrict__ at1, const float* __restrict__ at2,
                        ushort* __restrict__ tabh, const int* __restrict__ xidx,
                        int* __restrict__ xcode, float* __restrict__ out,
                        const float* __restrict__ bp) {
  int i = blockIdx.x * 256 + threadIdx.x;
  if (i < 40960) {  // weight swizzle, B-frag 16x16x32 order
    int lane = i & 63;
    int f = i >> 6;
    bool isW2 = false;
    if (f >= 320) { f -= 320; isW2 = true; }
    int l = f >> 6, rem = f & 63;
    ushort8 o;
    if (!isW2) {
      int kt = rem >> 4, nt = rem & 15;
      int n = nt * 16 + (lane & 15);
      int kbase = kt * 32 + (lane >> 4) * 8;
#pragma unroll
      for (int j = 0; j < 8; ++j) o[j] = f2h(W1[l * 32768 + (kbase + j) * 256 + n]);
      *(ushort8*)(w1s + f * 512 + lane * 8) = o;
    } else {
      int kt = rem >> 3, nt = rem & 7;
      int n = nt * 16 + (lane & 15);
      int kbase = kt * 32 + (lane >> 4) * 8;
#pragma unroll
      for (int j = 0; j < 8; ++j) o[j] = f2h(W2[l * 32768 + (kbase + j) * 128 + n]);
      *(ushort8*)(w2s + f * 512 + lane * 8) = o;
    }
  }
  if (i < 5760) {  // comb (packed fp16)
    int l = i / 1152, rem = i % 1152;
    int ab = rem >> 7, c = rem & 127;
    int a = ab / 3, b = ab - a * 3;
    tabh[i] = f2h(ee1[(l * 6 + a) * 128 + c] + ee2[(l * 3 + b) * 128 + c]);
  } else if (i < 6400) {  // selfv
    int j = i - 5760;
    int l = j >> 7, c = j & 127;
    tabh[i] = f2h(ee1[(l * 6 + 4) * 128 + c] + ee2[(l * 3 + 0) * 128 + c]);
  } else if (i < 7552) {  // atomc
    int j = i - 6400;
    int ab = j >> 7, c = j & 127;
    int a = ab / 3, b = ab - a * 3;
    tabh[i] = f2h(at1[a * 128 + c] + at2[b * 128 + c]);
  }
  if (i < NN) xcode[i] = xidx[2 * i] * 3 + xidx[2 * i + 1];
  if (i < GG) out[i] = bp[0];
}

// ---------------- CSR build (dst is fixed across layers) ----------------
__global__ void k_count(const int* __restrict__ ei, int* __restrict__ counts) {
  int e = blockIdx.x * 256 + threadIdx.x;
  if (e < EE) atomicAdd(&counts[ei[EE + e]], 1);
}

__global__ void k_scanA(const int* __restrict__ counts, int* __restrict__ rowptr,
                        int* __restrict__ bsums) {
  __shared__ int sd[256];
  int tid = threadIdx.x;
  int g = blockIdx.x * 256 + tid;
  int v = (g < NN) ? counts[g] : 0;
  sd[tid] = v;
  __syncthreads();
  for (int o = 1; o < 256; o <<= 1) {
    int t = (tid >= o) ? sd[tid - o] : 0;
    __syncthreads();
    sd[tid] += t;
    __syncthreads();
  }
  if (g < NN) rowptr[g] = sd[tid] - v;
  if (tid == 255) bsums[blockIdx.x] = sd[tid];
}

__global__ void k_scanB(int* __restrict__ bsums) {
  __shared__ int sd[1024];
  int tid = threadIdx.x;
  int v = (tid < SCAN_NB) ? bsums[tid] : 0;
  sd[tid] = v;
  __syncthreads();
  for (int o = 1; o < 1024; o <<= 1) {
    int t = (tid >= o) ? sd[tid - o] : 0;
    __syncthreads();
    sd[tid] += t;
    __syncthreads();
  }
  if (tid < SCAN_NB) bsums[tid] = sd[tid] - v;
}

__global__ void k_scanC(int* __restrict__ rowptr, const int* __restrict__ bsums) {
  int g = blockIdx.x * 256 + threadIdx.x;
  if (g < NN) rowptr[g] += bsums[blockIdx.x];
  if (g == 0) rowptr[NN] = EE;
}

// pack src (18b) | a9 (4b) | xcode_src (4b)
__global__ void k_fill(const int* __restrict__ ei, const int* __restrict__ ea,
                       const int* __restrict__ xcode, int* __restrict__ cursor,
                       int* __restrict__ eslot) {
  int e = blockIdx.x * 256 + threadIdx.x;
  if (e < EE) {
    int dst = ei[EE + e];
    int src = ei[e];
    int a9 = ea[2 * e] * 3 + ea[2 * e + 1];
    int sc = xcode[src];
    int pos = atomicAdd(&cursor[dst], 1);
    eslot[pos] = src | (a9 << 18) | (sc << 22);
  }
}

// ---------------- fused layer: packed-fp16 gather->LDS, fp16 MLP, BN stats --------
// r11 structure (best: 89.7 us/layer) with the gather arithmetic reduced to packed
// fp16 adds: zin already holds h = relu(z*sc+sh) (k_bnapply, in-place), so each
// edge is acc += h[src] +pk comb[a9] — 8 v_pk_add_f16/lane vs ~32 mixed ops.
// Block = 4 waves, 32 nodes, 16-lane sub-group per node, x2 unroll.
// LDS: 16.9 KB union (AGG/T1/ldsZ). launch_bounds(256,5): cap above natural usage.
__global__ __launch_bounds__(256, 5) void k_layer(
    const ushort* __restrict__ zin, ushort* __restrict__ zout,
    const int* __restrict__ xcode, const ushort* __restrict__ tabh,
    const int* __restrict__ rowptr, const int* __restrict__ eslot,
    const ushort* __restrict__ w1s, const ushort* __restrict__ w2s,
    const float* __restrict__ b1, const float* __restrict__ b2,
    float* __restrict__ stats, int layer) {
  __shared__ __align__(16) ushort BUF[32 * 264];  // 16,896 B union
  ushort* AGG = BUF;   // 32 x 136 view (gather out / stage-1 in)
  ushort* T1 = BUF;    // 32 x 264 view (stage-1 out / stage-2 in)
  ushort* ldsZ = BUF;  // 32 x 136 view (stage-2 out / store staging)
  const int tid = threadIdx.x;
  const int w = tid >> 6, lane = tid & 63;
  const int ln16 = lane & 15, sub = lane >> 4;
  const int row0 = blockIdx.x * 32;

  // ---- gather phase: all packed fp16 ----
  const uint4* combH = (const uint4*)(tabh + (size_t)layer * 1152);
  const uint4* atomH = (const uint4*)(tabh + 6400);
  const uint4* selfH = (const uint4*)(tabh + 5760 + layer * 128);
  const uint4* h4 = (const uint4*)zin;
  f16x8 sf = ld8h(selfH, ln16);

#pragma unroll
  for (int grp = 0; grp < 2; ++grp) {
    const int n = row0 + w * 8 + grp * 4 + sub;
    const int s = rowptr[n], e = rowptr[n + 1];
    f16x8 acc;
    if (layer == 0) {
      acc = ld8h(atomH, xcode[n] * 16 + ln16) + sf;
    } else {
      acc = ld8h(h4, (size_t)n * 16 + ln16) + sf;
    }
    for (int base = s; base < e; base += 16) {
      int m = e - base;
      if (m > 16) m = 16;
      int slot = (ln16 < m) ? eslot[base + ln16] : 0;
      int j = 0;
      for (; j + 2 <= m; j += 2) {
        int sl0 = __shfl(slot, sub * 16 + j, 64);
        int sl1 = __shfl(slot, sub * 16 + j + 1, 64);
        f16x8 p0, p1;
        if (layer == 0) {
          p0 = ld8h(atomH, ((sl0 >> 22) & 15) * 16 + ln16);
          p1 = ld8h(atomH, ((sl1 >> 22) & 15) * 16 + ln16);
        } else {
          p0 = ld8h(h4, (size_t)(sl0 & 0x3FFFF) * 16 + ln16);
          p1 = ld8h(h4, (size_t)(sl1 & 0x3FFFF) * 16 + ln16);
        }
        f16x8 c0 = ld8h(combH, ((sl0 >> 18) & 15) * 16 + ln16);
        f16x8 c1 = ld8h(combH, ((sl1 >> 18) & 15) * 16 + ln16);
        acc += p0 + c0;
        acc += p1 + c1;
      }
      if (j < m) {
        int sl = __shfl(slot, sub * 16 + j, 64);
        f16x8 p0;
        if (layer == 0) {
          p0 = ld8h(atomH, ((sl >> 22) & 15) * 16 + ln16);
        } else {
          p0 = ld8h(h4, (size_t)(sl & 0x3FFFF) * 16 + ln16);
        }
        f16x8 c0 = ld8h(combH, ((sl >> 18) & 15) * 16 + ln16);
        acc += p0 + c0;
      }
    }
    *(uint4*)&AGG[(w * 8 + grp * 4 + sub) * 136 + ln16 * 8] =
        __builtin_bit_cast(uint4, acc);
  }
  __syncthreads();

  // ---- MLP stage 1: acc = AGG @ W1, M=32, fp16 ----
  const int lm = ln16, q = sub;
  f32x4 acc[2][4] = {};
  const ushort* w1b = w1s + layer * 64 * 512;
#pragma unroll
  for (int kt = 0; kt < 4; ++kt) {
    f16x8 af[2], bf[4];
#pragma unroll
    for (int mt = 0; mt < 2; ++mt) {
      const ushort* p = AGG + (mt * 16 + lm) * 136 + kt * 32 + q * 8;
      af[mt] = __builtin_bit_cast(f16x8, *(const ushort8*)p);
    }
#pragma unroll
    for (int nt = 0; nt < 4; ++nt) {
      const ushort* p = w1b + (kt * 16 + w * 4 + nt) * 512 + lane * 8;
      bf[nt] = __builtin_bit_cast(f16x8, *(const ushort8*)p);
    }
#pragma unroll
    for (int mt = 0; mt < 2; ++mt)
#pragma unroll
      for (int nt = 0; nt < 4; ++nt)
        acc[mt][nt] = __builtin_amdgcn_mfma_f32_16x16x32_f16(af[mt], bf[nt], acc[mt][nt], 0, 0, 0);
  }
  __syncthreads();  // AGG dead; T1 may now overwrite the union buffer
#pragma unroll
  for (int nt = 0; nt < 4; ++nt) {
    int n = w * 64 + nt * 16 + lm;
    float bias = b1[layer * 256 + n];
#pragma unroll
    for (int mt = 0; mt < 2; ++mt)
#pragma unroll
      for (int r = 0; r < 4; ++r) {
        float v = fmaxf(acc[mt][nt][r] + bias, 0.0f);
        T1[(mt * 16 + q * 4 + r) * 264 + n] = f2h(v);
      }
  }
  __syncthreads();

  // ---- MLP stage 2: z = T1 @ W2 + b2, + BN stats epilogue ----
  f32x4 acc2[2][2] = {};
  const ushort* w2b = w2s + layer * 64 * 512;
#pragma unroll
  for (int kt = 0; kt < 8; ++kt) {
    f16x8 af[2], bf[2];
#pragma unroll
    for (int mt = 0; mt < 2; ++mt) {
      const ushort* p = T1 + (mt * 16 + lm) * 264 + kt * 32 + q * 8;
      af[mt] = __builtin_bit_cast(f16x8, *(const ushort8*)p);
    }
#pragma unroll
    for (int nt = 0; nt < 2; ++nt) {
      const ushort* p = w2b + (kt * 8 + w * 2 + nt) * 512 + lane * 8;
      bf[nt] = __builtin_bit_cast(f16x8, *(const ushort8*)p);
    }
#pragma unroll
    for (int mt = 0; mt < 2; ++mt)
#pragma unroll
      for (int nt = 0; nt < 2; ++nt)
        acc2[mt][nt] = __builtin_amdgcn_mfma_f32_16x16x32_f16(af[mt], bf[nt], acc2[mt][nt], 0, 0, 0);
  }
  __syncthreads();  // T1 dead; ldsZ may now overwrite the union buffer
  float ssum[2], ssq[2];
#pragma unroll
  for (int nt = 0; nt < 2; ++nt) {
    int n = w * 32 + nt * 16 + lm;
    float bias = b2[layer * 128 + n];
    ssum[nt] = 0.f;
    ssq[nt] = 0.f;
#pragma unroll
    for (int mt = 0; mt < 2; ++mt)
#pragma unroll
      for (int r = 0; r < 4; ++r) {
        float v = acc2[mt][nt][r] + bias;
        ldsZ[(mt * 16 + q * 4 + r) * 136 + n] = f2h(v);
        ssum[nt] += v;
        ssq[nt] += v * v;
      }
    ssum[nt] += __shfl_xor(ssum[nt], 16, 64);
    ssum[nt] += __shfl_xor(ssum[nt], 32, 64);
    ssq[nt] += __shfl_xor(ssq[nt], 16, 64);
    ssq[nt] += __shfl_xor(ssq[nt], 32, 64);
  }
  if (lane < 16) {
    int cp = blockIdx.x & 15;
    float* sb = stats + (size_t)(layer * 16 + cp) * 256;
#pragma unroll
    for (int nt = 0; nt < 2; ++nt) {
      int col = w * 32 + nt * 16 + lane;
      atomicAdd(&sb[col], ssum[nt]);
      atomicAdd(&sb[128 + col], ssq[nt]);
    }
  }
  __syncthreads();
  uint* zo = (uint*)zout;
  for (int i = tid; i < 32 * 64; i += 256) {
    int row = i >> 6, cpx = i & 63;
    uint v = *(const uint*)&ldsZ[row * 136 + cpx * 2];
    zo[(size_t)(row0 + row) * 64 + cpx] = v;
  }
}

__global__ void k_bnparam(const float* __restrict__ stats, const float* __restrict__ gamma,
                          const float* __restrict__ beta, float* __restrict__ bnscale,
                          float* __restrict__ bnshift, int layer) {
  int c = threadIdx.x;
  float s = 0.f, qv = 0.f;
  for (int cp = 0; cp < 16; ++cp) {
    const float* sb = stats + (size_t)(layer * 16 + cp) * 256;
    s += sb[c];
    qv += sb[128 + c];
  }
  float mu = s * (1.0f / NN);
  float var = qv * (1.0f / NN) - mu * mu;
  float sc = gamma[layer * 128 + c] * rsqrtf(var + 1e-5f);
  bnscale[layer * 128 + c] = sc;
  bnshift[layer * 128 + c] = beta[layer * 128 + c] - mu * sc;
}

// ---------------- bnapply: z -> h = relu(z*sc+sh), in place (layers 0..3) ---------
__global__ __launch_bounds__(256) void k_bnapply(ushort* __restrict__ z,
                                                 const float* __restrict__ bnscale,
                                                 const float* __restrict__ bnshift,
                                                 int layer) {
  int i = blockIdx.x * 256 + threadIdx.x;  // < NN*16, one uint4 (8 cols) each
  uint4* z4 = (uint4*)z;
  uint4 u = z4[i];
  int cg = (i & 15) << 3;
  const float4* scp = (const float4*)(bnscale + layer * 128 + cg);
  const float4* shp = (const float4*)(bnshift + layer * 128 + cg);
  float4 s0 = scp[0], s1 = scp[1];
  float4 t0 = shp[0], t1 = shp[1];
  uint4 r;
  r.x = (uint)f2h(fmaxf(fmaf(hlo(u.x), s0.x, t0.x), 0.f)) |
        ((uint)f2h(fmaxf(fmaf(hhi(u.x), s0.y, t0.y), 0.f)) << 16);
  r.y = (uint)f2h(fmaxf(fmaf(hlo(u.y), s0.z, t0.z), 0.f)) |
        ((uint)f2h(fmaxf(fmaf(hhi(u.y), s0.w, t0.w), 0.f)) << 16);
  r.z = (uint)f2h(fmaxf(fmaf(hlo(u.z), s1.x, t1.x), 0.f)) |
        ((uint)f2h(fmaxf(fmaf(hhi(u.z), s1.y, t1.y), 0.f)) << 16);
  r.w = (uint)f2h(fmaxf(fmaf(hlo(u.w), s1.z, t1.z), 0.f)) |
        ((uint)f2h(fmaxf(fmaf(hhi(u.w), s1.w, t1.w), 0.f)) << 16);
  z4[i] = r;
}

// ---------------- pooling with segmented running sum (batch sorted) ----------------
__global__ __launch_bounds__(256) void k_pool(const ushort* __restrict__ z,
                                              const float* __restrict__ bnscale,
                                              const float* __restrict__ bnshift,
                                              const int* __restrict__ batch,
                                              const float* __restrict__ Wp,
                                              float* __restrict__ out) {
  const int tid = threadIdx.x;
  const int w = tid >> 6, lane = tid & 63;
  const int nb = blockIdx.x * 64 + w * 16;
  float2 wp = ((const float2*)Wp)[lane];
  float2 scv = ((const float2*)(bnscale + 4 * 128))[lane];
  float2 shv = ((const float2*)(bnshift + 4 * 128))[lane];
  const uint* z32 = (const uint*)z;
  int bb = (lane < 16) ? batch[nb + lane] : 0;
  int curb = __shfl(bb, 0);
  float run = 0.f;
#pragma unroll
  for (int i = 0; i < 16; ++i) {
    int b = __shfl(bb, i);
    uint u = z32[(size_t)(nb + i) * 64 + lane];
    float dot = fmaf(hlo(u), scv.x, shv.x) * wp.x + fmaf(hhi(u), scv.y, shv.y) * wp.y;
#pragma unroll
    for (int off = 32; off > 0; off >>= 1) dot += __shfl_xor(dot, off, 64);
    if (b != curb) {
      if (lane == 0) atomicAdd(&out[curb], run);
      run = 0.f;
      curb = b;
    }
    run += dot;
  }
  if (lane == 0) atomicAdd(&out[curb], run);
}

extern "C" void kernel_launch(void* const* d_in, const int* in_sizes, int n_in,
                              void* d_out, int out_size, void* d_ws, size_t ws_size,
                              hipStream_t stream) {
  (void)in_sizes; (void)n_in; (void)out_size; (void)ws_size;
  const int* xidx = (const int*)d_in[0];
  const int* eidx = (const int*)d_in[1];
  const int* eattr = (const int*)d_in[2];
  const int* batch = (const int*)d_in[3];
  const float* at1 = (const float*)d_in[4];
  const float* at2 = (const float*)d_in[5];
  const float* ee1 = (const float*)d_in[6];
  const float* ee2 = (const float*)d_in[7];
  const float* W1 = (const float*)d_in[8];
  const float* b1 = (const float*)d_in[9];
  const float* W2 = (const float*)d_in[10];
  const float* b2 = (const float*)d_in[11];
  const float* gamma = (const float*)d_in[12];
  const float* beta = (const float*)d_in[13];
  const float* Wp = (const float*)d_in[14];
  const float* bp = (const float*)d_in[15];
  float* out = (float*)d_out;

  char* ws = (char*)d_ws;
  size_t off = 0;
  auto alloc = [&](size_t bytes) -> void* {
    void* p = ws + off;
    off = (off + bytes + 255) & ~(size_t)255;
    return p;
  };
  ushort* bufA = (ushort*)alloc((size_t)NN * 128 * 2);
  ushort* bufB = (ushort*)alloc((size_t)NN * 128 * 2);
  ushort* w1s = (ushort*)alloc(320 * 512 * 2);
  ushort* w2s = (ushort*)alloc(320 * 512 * 2);
  int* rowptr = (int*)alloc((NN + 1) * 4);
  int* cursor = (int*)alloc((size_t)NN * 4);
  int* eslot = (int*)alloc((size_t)EE * 4);
  int* bsums = (int*)alloc(1024 * 4);
  ushort* tabh = (ushort*)alloc(7552 * 2);
  int* xcode = (int*)alloc((size_t)NN * 4);
  float* stats = (float*)alloc((size_t)LL * 16 * 256 * 4);
  float* bnscale = (float*)alloc(LL * 128 * 4);
  float* bnshift = (float*)alloc(LL * 128 * 4);

  hipMemsetAsync(cursor, 0, (size_t)NN * 4, stream);
  hipMemsetAsync(stats, 0, (size_t)LL * 16 * 256 * 4, stream);
  k_setup<<<SCAN_NB, 256, 0, stream>>>(W1, W2, w1s, w2s, ee1, ee2, at1, at2, tabh, xidx,
                                       xcode, out, bp);
  k_count<<<(EE + 255) / 256, 256, 0, stream>>>(eidx, cursor);
  k_scanA<<<SCAN_NB, 256, 0, stream>>>(cursor, rowptr, bsums);
  k_scanB<<<1, 1024, 0, stream>>>(bsums);
  k_scanC<<<SCAN_NB, 256, 0, stream>>>(rowptr, bsums);
  hipMemcpyAsync(cursor, rowptr, (size_t)NN * 4, hipMemcpyDeviceToDevice, stream);
  k_fill<<<(EE + 255) / 256, 256, 0, stream>>>(eidx, eattr, xcode, cursor, eslot);

  for (int l = 0; l < LL; ++l) {
    ushort* zo = (l & 1) ? bufB : bufA;
    const ushort* zi = (l & 1) ? bufA : bufB;  // h_{l-1} (bnapplied); unused for l==0
    k_layer<<<NN / 32, 256, 0, stream>>>((l == 0) ? bufA : zi, zo, xcode, tabh, rowptr,
                                         eslot, w1s, w2s, b1, b2, stats, l);
    k_bnparam<<<1, 128, 0, stream>>>(stats, gamma, beta, bnscale, bnshift, l);
    if (l < LL - 1)
      k_bnapply<<<NN * 16 / 256, 256, 0, stream>>>(zo, bnscale, bnshift, l);
  }
  k_pool<<<NN / 64, 256, 0, stream>>>(bufA, bnscale, bnshift, batch, Wp, out);
}

// Round 14
// 602.459 us; speedup vs baseline: 1.1659x; 1.0135x over previous
//
#include <hip/hip_runtime.h>

typedef unsigned int uint;
typedef unsigned short ushort;
typedef _Float16 f16_t;
typedef f16_t f16x8 __attribute__((ext_vector_type(8)));
typedef ushort ushort8 __attribute__((ext_vector_type(8)));
typedef float f32x4 __attribute__((ext_vector_type(4)));

#define NN 200000
#define EE 600000
#define LL 5
#define GG 2000
#define SCAN_NB 782  // ceil(NN/256)

__device__ __forceinline__ ushort f2h(float f) {
  f16_t h = (f16_t)f;
  return __builtin_bit_cast(ushort, h);
}
__device__ __forceinline__ float h2f(ushort u) {
  return (float)__builtin_bit_cast(f16_t, u);
}
__device__ __forceinline__ float hlo(uint u) { return h2f((ushort)(u & 0xFFFFu)); }
__device__ __forceinline__ float hhi(uint u) { return h2f((ushort)(u >> 16)); }
__device__ __forceinline__ f16x8 ld8h(const uint4* p, int idx) {
  uint4 u = p[idx];
  return __builtin_bit_cast(f16x8, u);
}

// ---------------- merged setup: weight swizzle + fp16 tables + xcode + outinit ------
__global__ void k_setup(const float* __restrict__ W1, const float* __restrict__ W2,
                        ushort* __restrict__ w1s, ushort* __restrict__ w2s,
                        const float* __restrict__ ee1, const float* __restrict__ ee2,
                        const float* __restrict__ at1, const float* __restrict__ at2,
                        ushort* __restrict__ tabh, const int* __restrict__ xidx,
                        int* __restrict__ xcode, float* __restrict__ out,
                        const float* __restrict__ bp) {
  int i = blockIdx.x * 256 + threadIdx.x;
  if (i < 40960) {  // weight swizzle, B-frag 16x16x32 order
    int lane = i & 63;
    int f = i >> 6;
    bool isW2 = false;
    if (f >= 320) { f -= 320; isW2 = true; }
    int l = f >> 6, rem = f & 63;
    ushort8 o;
    if (!isW2) {
      int kt = rem >> 4, nt = rem & 15;
      int n = nt * 16 + (lane & 15);
      int kbase = kt * 32 + (lane >> 4) * 8;
#pragma unroll
      for (int j = 0; j < 8; ++j) o[j] = f2h(W1[l * 32768 + (kbase + j) * 256 + n]);
      *(ushort8*)(w1s + f * 512 + lane * 8) = o;
    } else {
      int kt = rem >> 3, nt = rem & 7;
      int n = nt * 16 + (lane & 15);
      int kbase = kt * 32 + (lane >> 4) * 8;
#pragma unroll
      for (int j = 0; j < 8; ++j) o[j] = f2h(W2[l * 32768 + (kbase + j) * 128 + n]);
      *(ushort8*)(w2s + f * 512 + lane * 8) = o;
    }
  }
  if (i < 5760) {  // comb (packed fp16)
    int l = i / 1152, rem = i % 1152;
    int ab = rem >> 7, c = rem & 127;
    int a = ab / 3, b = ab - a * 3;
    tabh[i] = f2h(ee1[(l * 6 + a) * 128 + c] + ee2[(l * 3 + b) * 128 + c]);
  } else if (i < 6400) {  // selfv
    int j = i - 5760;
    int l = j >> 7, c = j & 127;
    tabh[i] = f2h(ee1[(l * 6 + 4) * 128 + c] + ee2[(l * 3 + 0) * 128 + c]);
  } else if (i < 7552) {  // atomc
    int j = i - 6400;
    int ab = j >> 7, c = j & 127;
    int a = ab / 3, b = ab - a * 3;
    tabh[i] = f2h(at1[a * 128 + c] + at2[b * 128 + c]);
  }
  if (i < NN) xcode[i] = xidx[2 * i] * 3 + xidx[2 * i + 1];
  if (i < GG) out[i] = bp[0];
}

// ---------------- CSR build (dst is fixed across layers) ----------------
__global__ void k_count(const int* __restrict__ ei, int* __restrict__ counts) {
  int e = blockIdx.x * 256 + threadIdx.x;
  if (e < EE) atomicAdd(&counts[ei[EE + e]], 1);
}

__global__ void k_scanA(const int* __restrict__ counts, int* __restrict__ rowptr,
                        int* __restrict__ bsums) {
  __shared__ int sd[256];
  int tid = threadIdx.x;
  int g = blockIdx.x * 256 + tid;
  int v = (g < NN) ? counts[g] : 0;
  sd[tid] = v;
  __syncthreads();
  for (int o = 1; o < 256; o <<= 1) {
    int t = (tid >= o) ? sd[tid - o] : 0;
    __syncthreads();
    sd[tid] += t;
    __syncthreads();
  }
  if (g < NN) rowptr[g] = sd[tid] - v;
  if (tid == 255) bsums[blockIdx.x] = sd[tid];
}

__global__ void k_scanB(int* __restrict__ bsums) {
  __shared__ int sd[1024];
  int tid = threadIdx.x;
  int v = (tid < SCAN_NB) ? bsums[tid] : 0;
  sd[tid] = v;
  __syncthreads();
  for (int o = 1; o < 1024; o <<= 1) {
    int t = (tid >= o) ? sd[tid - o] : 0;
    __syncthreads();
    sd[tid] += t;
    __syncthreads();
  }
  if (tid < SCAN_NB) bsums[tid] = sd[tid] - v;
}

__global__ void k_scanC(int* __restrict__ rowptr, const int* __restrict__ bsums) {
  int g = blockIdx.x * 256 + threadIdx.x;
  if (g < NN) rowptr[g] += bsums[blockIdx.x];
  if (g == 0) rowptr[NN] = EE;
}

// pack src (18b) | a9 (4b) | xcode_src (4b)
__global__ void k_fill(const int* __restrict__ ei, const int* __restrict__ ea,
                       const int* __restrict__ xcode, int* __restrict__ cursor,
                       int* __restrict__ eslot) {
  int e = blockIdx.x * 256 + threadIdx.x;
  if (e < EE) {
    int dst = ei[EE + e];
    int src = ei[e];
    int a9 = ea[2 * e] * 3 + ea[2 * e + 1];
    int sc = xcode[src];
    int pos = atomicAdd(&cursor[dst], 1);
    eslot[pos] = src | (a9 << 18) | (sc << 22);
  }
}

// ---------------- fused layer: packed-fp16 gather->LDS, fp16 MLP, BN stats --------
// zin holds h = relu(z*sc+sh) (k_bnfix, in-place); per edge: acc += h[src] + comb.
// Edge loop unrolled x4 — viable now because the packed payload set is small
// (~60 regs vs f32 version's 130+ which spilled in r8/r10). Verdict counter:
// FETCH/WRITE must stay ~98/56 MB.
// Block = 4 waves, 32 nodes, 16-lane sub-group per node.
// LDS: 16.9 KB union (AGG/T1/ldsZ). launch_bounds(256,5): cap above natural usage.
__global__ __launch_bounds__(256, 5) void k_layer(
    const ushort* __restrict__ zin, ushort* __restrict__ zout,
    const int* __restrict__ xcode, const ushort* __restrict__ tabh,
    const int* __restrict__ rowptr, const int* __restrict__ eslot,
    const ushort* __restrict__ w1s, const ushort* __restrict__ w2s,
    const float* __restrict__ b1, const float* __restrict__ b2,
    float* __restrict__ stats, int layer) {
  __shared__ __align__(16) ushort BUF[32 * 264];  // 16,896 B union
  ushort* AGG = BUF;   // 32 x 136 view (gather out / stage-1 in)
  ushort* T1 = BUF;    // 32 x 264 view (stage-1 out / stage-2 in)
  ushort* ldsZ = BUF;  // 32 x 136 view (stage-2 out / store staging)
  const int tid = threadIdx.x;
  const int w = tid >> 6, lane = tid & 63;
  const int ln16 = lane & 15, sub = lane >> 4;
  const int row0 = blockIdx.x * 32;

  // ---- gather phase: all packed fp16 ----
  const uint4* combH = (const uint4*)(tabh + (size_t)layer * 1152);
  const uint4* atomH = (const uint4*)(tabh + 6400);
  const uint4* selfH = (const uint4*)(tabh + 5760 + layer * 128);
  const uint4* h4 = (const uint4*)zin;
  f16x8 sf = ld8h(selfH, ln16);

#pragma unroll
  for (int grp = 0; grp < 2; ++grp) {
    const int n = row0 + w * 8 + grp * 4 + sub;
    const int s = rowptr[n], e = rowptr[n + 1];
    f16x8 acc;
    if (layer == 0) {
      acc = ld8h(atomH, xcode[n] * 16 + ln16) + sf;
    } else {
      acc = ld8h(h4, (size_t)n * 16 + ln16) + sf;
    }
    for (int base = s; base < e; base += 16) {
      int m = e - base;
      if (m > 16) m = 16;
      int slot = (ln16 < m) ? eslot[base + ln16] : 0;
      int j = 0;
      for (; j + 4 <= m; j += 4) {  // 4 rows in flight per sub-group
        int sl0 = __shfl(slot, sub * 16 + j, 64);
        int sl1 = __shfl(slot, sub * 16 + j + 1, 64);
        int sl2 = __shfl(slot, sub * 16 + j + 2, 64);
        int sl3 = __shfl(slot, sub * 16 + j + 3, 64);
        f16x8 p0, p1, p2, p3;
        if (layer == 0) {
          p0 = ld8h(atomH, ((sl0 >> 22) & 15) * 16 + ln16);
          p1 = ld8h(atomH, ((sl1 >> 22) & 15) * 16 + ln16);
          p2 = ld8h(atomH, ((sl2 >> 22) & 15) * 16 + ln16);
          p3 = ld8h(atomH, ((sl3 >> 22) & 15) * 16 + ln16);
        } else {
          p0 = ld8h(h4, (size_t)(sl0 & 0x3FFFF) * 16 + ln16);
          p1 = ld8h(h4, (size_t)(sl1 & 0x3FFFF) * 16 + ln16);
          p2 = ld8h(h4, (size_t)(sl2 & 0x3FFFF) * 16 + ln16);
          p3 = ld8h(h4, (size_t)(sl3 & 0x3FFFF) * 16 + ln16);
        }
        f16x8 c0 = ld8h(combH, ((sl0 >> 18) & 15) * 16 + ln16);
        f16x8 c1 = ld8h(combH, ((sl1 >> 18) & 15) * 16 + ln16);
        f16x8 c2 = ld8h(combH, ((sl2 >> 18) & 15) * 16 + ln16);
        f16x8 c3 = ld8h(combH, ((sl3 >> 18) & 15) * 16 + ln16);
        acc += p0 + c0;
        acc += p1 + c1;
        acc += p2 + c2;
        acc += p3 + c3;
      }
      for (; j + 2 <= m; j += 2) {
        int sl0 = __shfl(slot, sub * 16 + j, 64);
        int sl1 = __shfl(slot, sub * 16 + j + 1, 64);
        f16x8 p0, p1;
        if (layer == 0) {
          p0 = ld8h(atomH, ((sl0 >> 22) & 15) * 16 + ln16);
          p1 = ld8h(atomH, ((sl1 >> 22) & 15) * 16 + ln16);
        } else {
          p0 = ld8h(h4, (size_t)(sl0 & 0x3FFFF) * 16 + ln16);
          p1 = ld8h(h4, (size_t)(sl1 & 0x3FFFF) * 16 + ln16);
        }
        f16x8 c0 = ld8h(combH, ((sl0 >> 18) & 15) * 16 + ln16);
        f16x8 c1 = ld8h(combH, ((sl1 >> 18) & 15) * 16 + ln16);
        acc += p0 + c0;
        acc += p1 + c1;
      }
      if (j < m) {
        int sl = __shfl(slot, sub * 16 + j, 64);
        f16x8 p0;
        if (layer == 0) {
          p0 = ld8h(atomH, ((sl >> 22) & 15) * 16 + ln16);
        } else {
          p0 = ld8h(h4, (size_t)(sl & 0x3FFFF) * 16 + ln16);
        }
        f16x8 c0 = ld8h(combH, ((sl >> 18) & 15) * 16 + ln16);
        acc += p0 + c0;
      }
    }
    *(uint4*)&AGG[(w * 8 + grp * 4 + sub) * 136 + ln16 * 8] =
        __builtin_bit_cast(uint4, acc);
  }
  __syncthreads();

  // ---- MLP stage 1: acc = AGG @ W1, M=32, fp16 ----
  const int lm = ln16, q = sub;
  f32x4 acc[2][4] = {};
  const ushort* w1b = w1s + layer * 64 * 512;
#pragma unroll
  for (int kt = 0; kt < 4; ++kt) {
    f16x8 af[2], bf[4];
#pragma unroll
    for (int mt = 0; mt < 2; ++mt) {
      const ushort* p = AGG + (mt * 16 + lm) * 136 + kt * 32 + q * 8;
      af[mt] = __builtin_bit_cast(f16x8, *(const ushort8*)p);
    }
#pragma unroll
    for (int nt = 0; nt < 4; ++nt) {
      const ushort* p = w1b + (kt * 16 + w * 4 + nt) * 512 + lane * 8;
      bf[nt] = __builtin_bit_cast(f16x8, *(const ushort8*)p);
    }
#pragma unroll
    for (int mt = 0; mt < 2; ++mt)
#pragma unroll
      for (int nt = 0; nt < 4; ++nt)
        acc[mt][nt] = __builtin_amdgcn_mfma_f32_16x16x32_f16(af[mt], bf[nt], acc[mt][nt], 0, 0, 0);
  }
  __syncthreads();  // AGG dead; T1 may now overwrite the union buffer
#pragma unroll
  for (int nt = 0; nt < 4; ++nt) {
    int n = w * 64 + nt * 16 + lm;
    float bias = b1[layer * 256 + n];
#pragma unroll
    for (int mt = 0; mt < 2; ++mt)
#pragma unroll
      for (int r = 0; r < 4; ++r) {
        float v = fmaxf(acc[mt][nt][r] + bias, 0.0f);
        T1[(mt * 16 + q * 4 + r) * 264 + n] = f2h(v);
      }
  }
  __syncthreads();

  // ---- MLP stage 2: z = T1 @ W2 + b2, + BN stats epilogue ----
  f32x4 acc2[2][2] = {};
  const ushort* w2b = w2s + layer * 64 * 512;
#pragma unroll
  for (int kt = 0; kt < 8; ++kt) {
    f16x8 af[2], bf[2];
#pragma unroll
    for (int mt = 0; mt < 2; ++mt) {
      const ushort* p = T1 + (mt * 16 + lm) * 264 + kt * 32 + q * 8;
      af[mt] = __builtin_bit_cast(f16x8, *(const ushort8*)p);
    }
#pragma unroll
    for (int nt = 0; nt < 2; ++nt) {
      const ushort* p = w2b + (kt * 8 + w * 2 + nt) * 512 + lane * 8;
      bf[nt] = __builtin_bit_cast(f16x8, *(const ushort8*)p);
    }
#pragma unroll
    for (int mt = 0; mt < 2; ++mt)
#pragma unroll
      for (int nt = 0; nt < 2; ++nt)
        acc2[mt][nt] = __builtin_amdgcn_mfma_f32_16x16x32_f16(af[mt], bf[nt], acc2[mt][nt], 0, 0, 0);
  }
  __syncthreads();  // T1 dead; ldsZ may now overwrite the union buffer
  float ssum[2], ssq[2];
#pragma unroll
  for (int nt = 0; nt < 2; ++nt) {
    int n = w * 32 + nt * 16 + lm;
    float bias = b2[layer * 128 + n];
    ssum[nt] = 0.f;
    ssq[nt] = 0.f;
#pragma unroll
    for (int mt = 0; mt < 2; ++mt)
#pragma unroll
      for (int r = 0; r < 4; ++r) {
        float v = acc2[mt][nt][r] + bias;
        ldsZ[(mt * 16 + q * 4 + r) * 136 + n] = f2h(v);
        ssum[nt] += v;
        ssq[nt] += v * v;
      }
    ssum[nt] += __shfl_xor(ssum[nt], 16, 64);
    ssum[nt] += __shfl_xor(ssum[nt], 32, 64);
    ssq[nt] += __shfl_xor(ssq[nt], 16, 64);
    ssq[nt] += __shfl_xor(ssq[nt], 32, 64);
  }
  if (lane < 16) {
    int cp = blockIdx.x & 15;
    float* sb = stats + (size_t)(layer * 16 + cp) * 256;
#pragma unroll
    for (int nt = 0; nt < 2; ++nt) {
      int col = w * 32 + nt * 16 + lane;
      atomicAdd(&sb[col], ssum[nt]);
      atomicAdd(&sb[128 + col], ssq[nt]);
    }
  }
  __syncthreads();
  uint* zo = (uint*)zout;
  for (int i = tid; i < 32 * 64; i += 256) {
    int row = i >> 6, cpx = i & 63;
    uint v = *(const uint*)&ldsZ[row * 136 + cpx * 2];
    zo[(size_t)(row0 + row) * 64 + cpx] = v;
  }
}

// ---------------- bnparam (layer 4 only, for pool) ----------------
__global__ void k_bnparam(const float* __restrict__ stats, const float* __restrict__ gamma,
                          const float* __restrict__ beta, float* __restrict__ bnscale,
                          float* __restrict__ bnshift, int layer) {
  int c = threadIdx.x;
  float s = 0.f, qv = 0.f;
  for (int cp = 0; cp < 16; ++cp) {
    const float* sb = stats + (size_t)(layer * 16 + cp) * 256;
    s += sb[c];
    qv += sb[128 + c];
  }
  float mu = s * (1.0f / NN);
  float var = qv * (1.0f / NN) - mu * mu;
  float sc = gamma[layer * 128 + c] * rsqrtf(var + 1e-5f);
  bnscale[layer * 128 + c] = sc;
  bnshift[layer * 128 + c] = beta[layer * 128 + c] - mu * sc;
}

// ---------------- bnfix: param compute (preamble) + z -> relu(z*sc+sh) in place ----
// Replaces the k_bnparam+k_bnapply pair for layers 0..3 (removes 1-block dispatch
// bubble). Preamble reduces the 16 stats copies in the SAME fp32 order. Grid-stride
// with stride % (16*256)==0 makes each thread's column group loop-invariant.
#define BNFIX_NB 1024
__global__ __launch_bounds__(256) void k_bnfix(ushort* __restrict__ z,
                                               const float* __restrict__ stats,
                                               const float* __restrict__ gamma,
                                               const float* __restrict__ beta,
                                               int layer) {
  __shared__ float S[128], T[128];
  const int tid = threadIdx.x;
  {
    int c = tid & 127, kind = tid >> 7;
    float v = 0.f;
    const float* sb = stats + (size_t)layer * 4096 + kind * 128 + c;
#pragma unroll
    for (int cp = 0; cp < 16; ++cp) v += sb[cp * 256];
    if (kind == 0) S[c] = v; else T[c] = v;
    __syncthreads();
    if (tid < 128) {
      float s = S[tid], qv = T[tid];
      float mu = s * (1.0f / NN);
      float var = qv * (1.0f / NN) - mu * mu;
      float sc = gamma[layer * 128 + tid] * rsqrtf(var + 1e-5f);
      S[tid] = sc;
      T[tid] = beta[layer * 128 + tid] - mu * sc;
    }
    __syncthreads();
  }
  int i0 = blockIdx.x * 256 + tid;
  int cg = (i0 & 15) << 3;
  float4 s0 = *(const float4*)&S[cg], s1 = *(const float4*)&S[cg + 4];
  float4 t0 = *(const float4*)&T[cg], t1 = *(const float4*)&T[cg + 4];
  uint4* z4 = (uint4*)z;
  for (int i = i0; i < NN * 16; i += BNFIX_NB * 256) {
    uint4 u = z4[i];
    uint4 r;
    r.x = (uint)f2h(fmaxf(fmaf(hlo(u.x), s0.x, t0.x), 0.f)) |
          ((uint)f2h(fmaxf(fmaf(hhi(u.x), s0.y, t0.y), 0.f)) << 16);
    r.y = (uint)f2h(fmaxf(fmaf(hlo(u.y), s0.z, t0.z), 0.f)) |
          ((uint)f2h(fmaxf(fmaf(hhi(u.y), s0.w, t0.w), 0.f)) << 16);
    r.z = (uint)f2h(fmaxf(fmaf(hlo(u.z), s1.x, t1.x), 0.f)) |
          ((uint)f2h(fmaxf(fmaf(hhi(u.z), s1.y, t1.y), 0.f)) << 16);
    r.w = (uint)f2h(fmaxf(fmaf(hlo(u.w), s1.z, t1.z), 0.f)) |
          ((uint)f2h(fmaxf(fmaf(hhi(u.w), s1.w, t1.w), 0.f)) << 16);
    z4[i] = r;
  }
}

// ---------------- pooling with segmented running sum (batch sorted) ----------------
__global__ __launch_bounds__(256) void k_pool(const ushort* __restrict__ z,
                                              const float* __restrict__ bnscale,
                                              const float* __restrict__ bnshift,
                                              const int* __restrict__ batch,
                                              const float* __restrict__ Wp,
                                              float* __restrict__ out) {
  const int tid = threadIdx.x;
  const int w = tid >> 6, lane = tid & 63;
  const int nb = blockIdx.x * 64 + w * 16;
  float2 wp = ((const float2*)Wp)[lane];
  float2 scv = ((const float2*)(bnscale + 4 * 128))[lane];
  float2 shv = ((const float2*)(bnshift + 4 * 128))[lane];
  const uint* z32 = (const uint*)z;
  int bb = (lane < 16) ? batch[nb + lane] : 0;
  int curb = __shfl(bb, 0);
  float run = 0.f;
#pragma unroll
  for (int i = 0; i < 16; ++i) {
    int b = __shfl(bb, i);
    uint u = z32[(size_t)(nb + i) * 64 + lane];
    float dot = fmaf(hlo(u), scv.x, shv.x) * wp.x + fmaf(hhi(u), scv.y, shv.y) * wp.y;
#pragma unroll
    for (int off = 32; off > 0; off >>= 1) dot += __shfl_xor(dot, off, 64);
    if (b != curb) {
      if (lane == 0) atomicAdd(&out[curb], run);
      run = 0.f;
      curb = b;
    }
    run += dot;
  }
  if (lane == 0) atomicAdd(&out[curb], run);
}

extern "C" void kernel_launch(void* const* d_in, const int* in_sizes, int n_in,
                              void* d_out, int out_size, void* d_ws, size_t ws_size,
                              hipStream_t stream) {
  (void)in_sizes; (void)n_in; (void)out_size; (void)ws_size;
  const int* xidx = (const int*)d_in[0];
  const int* eidx = (const int*)d_in[1];
  const int* eattr = (const int*)d_in[2];
  const int* batch = (const int*)d_in[3];
  const float* at1 = (const float*)d_in[4];
  const float* at2 = (const float*)d_in[5];
  const float* ee1 = (const float*)d_in[6];
  const float* ee2 = (const float*)d_in[7];
  const float* W1 = (const float*)d_in[8];
  const float* b1 = (const float*)d_in[9];
  const float* W2 = (const float*)d_in[10];
  const float* b2 = (const float*)d_in[11];
  const float* gamma = (const float*)d_in[12];
  const float* beta = (const float*)d_in[13];
  const float* Wp = (const float*)d_in[14];
  const float* bp = (const float*)d_in[15];
  float* out = (float*)d_out;

  char* ws = (char*)d_ws;
  size_t off = 0;
  auto alloc = [&](size_t bytes) -> void* {
    void* p = ws + off;
    off = (off + bytes + 255) & ~(size_t)255;
    return p;
  };
  ushort* bufA = (ushort*)alloc((size_t)NN * 128 * 2);
  ushort* bufB = (ushort*)alloc((size_t)NN * 128 * 2);
  ushort* w1s = (ushort*)alloc(320 * 512 * 2);
  ushort* w2s = (ushort*)alloc(320 * 512 * 2);
  int* rowptr = (int*)alloc((NN + 1) * 4);
  int* cursor = (int*)alloc((size_t)NN * 4);
  int* eslot = (int*)alloc((size_t)EE * 4);
  int* bsums = (int*)alloc(1024 * 4);
  ushort* tabh = (ushort*)alloc(7552 * 2);
  int* xcode = (int*)alloc((size_t)NN * 4);
  float* stats = (float*)alloc((size_t)LL * 16 * 256 * 4);
  float* bnscale = (float*)alloc(LL * 128 * 4);
  float* bnshift = (float*)alloc(LL * 128 * 4);

  hipMemsetAsync(cursor, 0, (size_t)NN * 4, stream);
  hipMemsetAsync(stats, 0, (size_t)LL * 16 * 256 * 4, stream);
  k_setup<<<SCAN_NB, 256, 0, stream>>>(W1, W2, w1s, w2s, ee1, ee2, at1, at2, tabh, xidx,
                                       xcode, out, bp);
  k_count<<<(EE + 255) / 256, 256, 0, stream>>>(eidx, cursor);
  k_scanA<<<SCAN_NB, 256, 0, stream>>>(cursor, rowptr, bsums);
  k_scanB<<<1, 1024, 0, stream>>>(bsums);
  k_scanC<<<SCAN_NB, 256, 0, stream>>>(rowptr, bsums);
  hipMemcpyAsync(cursor, rowptr, (size_t)NN * 4, hipMemcpyDeviceToDevice, stream);
  k_fill<<<(EE + 255) / 256, 256, 0, stream>>>(eidx, eattr, xcode, cursor, eslot);

  for (int l = 0; l < LL; ++l) {
    ushort* zo = (l & 1) ? bufB : bufA;
    const ushort* zi = (l & 1) ? bufA : bufB;  // h_{l-1} (bn-applied); unused for l==0
    k_layer<<<NN / 32, 256, 0, stream>>>((l == 0) ? bufA : zi, zo, xcode, tabh, rowptr,
                                         eslot, w1s, w2s, b1, b2, stats, l);
    if (l < LL - 1)
      k_bnfix<<<BNFIX_NB, 256, 0, stream>>>(zo, stats, gamma, beta, l);
  }
  k_bnparam<<<1, 128, 0, stream>>>(stats, gamma, beta, bnscale, bnshift, 4);
  k_pool<<<NN / 64, 256, 0, stream>>>(bufA, bnscale, bnshift, batch, Wp, out);
}

// Round 15
// 574.331 us; speedup vs baseline: 1.2230x; 1.0490x over previous
//
#include <hip/hip_runtime.h>

typedef unsigned int uint;
typedef unsigned short ushort;
typedef _Float16 f16_t;
typedef f16_t f16x8 __attribute__((ext_vector_type(8)));
typedef ushort ushort8 __attribute__((ext_vector_type(8)));
typedef float f32x4 __attribute__((ext_vector_type(4)));

#define NN 200000
#define EE 600000
#define LL 5
#define GG 2000
#define SCAN_NB 782  // ceil(NN/256)

__device__ __forceinline__ ushort f2h(float f) {
  f16_t h = (f16_t)f;
  return __builtin_bit_cast(ushort, h);
}
__device__ __forceinline__ float h2f(ushort u) {
  return (float)__builtin_bit_cast(f16_t, u);
}
__device__ __forceinline__ float hlo(uint u) { return h2f((ushort)(u & 0xFFFFu)); }
__device__ __forceinline__ float hhi(uint u) { return h2f((ushort)(u >> 16)); }
__device__ __forceinline__ f16x8 ld8h(const uint4* p, int idx) {
  uint4 u = p[idx];
  return __builtin_bit_cast(f16x8, u);
}
// h = relu(z*sc+sh) in packed fp16 (v_pk_fma_f16 + v_pk_max_f16)
__device__ __forceinline__ f16x8 bnrelu8(f16x8 u, f16x8 sc, f16x8 sh) {
  f16x8 r = u * sc + sh;
#pragma unroll
  for (int j = 0; j < 8; ++j) r[j] = r[j] > (f16_t)0.f ? r[j] : (f16_t)0.f;
  return r;
}

// ---------------- merged setup: weight swizzle + fp16 tables + xcode + outinit ------
__global__ void k_setup(const float* __restrict__ W1, const float* __restrict__ W2,
                        ushort* __restrict__ w1s, ushort* __restrict__ w2s,
                        const float* __restrict__ ee1, const float* __restrict__ ee2,
                        const float* __restrict__ at1, const float* __restrict__ at2,
                        ushort* __restrict__ tabh, const int* __restrict__ xidx,
                        int* __restrict__ xcode, float* __restrict__ out,
                        const float* __restrict__ bp) {
  int i = blockIdx.x * 256 + threadIdx.x;
  if (i < 40960) {  // weight swizzle, B-frag 16x16x32 order
    int lane = i & 63;
    int f = i >> 6;
    bool isW2 = false;
    if (f >= 320) { f -= 320; isW2 = true; }
    int l = f >> 6, rem = f & 63;
    ushort8 o;
    if (!isW2) {
      int kt = rem >> 4, nt = rem & 15;
      int n = nt * 16 + (lane & 15);
      int kbase = kt * 32 + (lane >> 4) * 8;
#pragma unroll
      for (int j = 0; j < 8; ++j) o[j] = f2h(W1[l * 32768 + (kbase + j) * 256 + n]);
      *(ushort8*)(w1s + f * 512 + lane * 8) = o;
    } else {
      int kt = rem >> 3, nt = rem & 7;
      int n = nt * 16 + (lane & 15);
      int kbase = kt * 32 + (lane >> 4) * 8;
#pragma unroll
      for (int j = 0; j < 8; ++j) o[j] = f2h(W2[l * 32768 + (kbase + j) * 128 + n]);
      *(ushort8*)(w2s + f * 512 + lane * 8) = o;
    }
  }
  if (i < 5760) {  // comb (packed fp16)
    int l = i / 1152, rem = i % 1152;
    int ab = rem >> 7, c = rem & 127;
    int a = ab / 3, b = ab - a * 3;
    tabh[i] = f2h(ee1[(l * 6 + a) * 128 + c] + ee2[(l * 3 + b) * 128 + c]);
  } else if (i < 6400) {  // selfv
    int j = i - 5760;
    int l = j >> 7, c = j & 127;
    tabh[i] = f2h(ee1[(l * 6 + 4) * 128 + c] + ee2[(l * 3 + 0) * 128 + c]);
  } else if (i < 7552) {  // atomc
    int j = i - 6400;
    int ab = j >> 7, c = j & 127;
    int a = ab / 3, b = ab - a * 3;
    tabh[i] = f2h(at1[a * 128 + c] + at2[b * 128 + c]);
  }
  if (i < NN) xcode[i] = xidx[2 * i] * 3 + xidx[2 * i + 1];
  if (i < GG) out[i] = bp[0];
}

// ---------------- CSR build (dst is fixed across layers) ----------------
__global__ void k_count(const int* __restrict__ ei, int* __restrict__ counts) {
  int e = blockIdx.x * 256 + threadIdx.x;
  if (e < EE) atomicAdd(&counts[ei[EE + e]], 1);
}

__global__ void k_scanA(const int* __restrict__ counts, int* __restrict__ rowptr,
                        int* __restrict__ bsums) {
  __shared__ int sd[256];
  int tid = threadIdx.x;
  int g = blockIdx.x * 256 + tid;
  int v = (g < NN) ? counts[g] : 0;
  sd[tid] = v;
  __syncthreads();
  for (int o = 1; o < 256; o <<= 1) {
    int t = (tid >= o) ? sd[tid - o] : 0;
    __syncthreads();
    sd[tid] += t;
    __syncthreads();
  }
  if (g < NN) rowptr[g] = sd[tid] - v;
  if (tid == 255) bsums[blockIdx.x] = sd[tid];
}

__global__ void k_scanB(int* __restrict__ bsums) {
  __shared__ int sd[1024];
  int tid = threadIdx.x;
  int v = (tid < SCAN_NB) ? bsums[tid] : 0;
  sd[tid] = v;
  __syncthreads();
  for (int o = 1; o < 1024; o <<= 1) {
    int t = (tid >= o) ? sd[tid - o] : 0;
    __syncthreads();
    sd[tid] += t;
    __syncthreads();
  }
  if (tid < SCAN_NB) bsums[tid] = sd[tid] - v;
}

__global__ void k_scanC(int* __restrict__ rowptr, const int* __restrict__ bsums) {
  int g = blockIdx.x * 256 + threadIdx.x;
  if (g < NN) rowptr[g] += bsums[blockIdx.x];
  if (g == 0) rowptr[NN] = EE;
}

// pack src (18b) | a9 (4b) | xcode_src (4b)
__global__ void k_fill(const int* __restrict__ ei, const int* __restrict__ ea,
                       const int* __restrict__ xcode, int* __restrict__ cursor,
                       int* __restrict__ eslot) {
  int e = blockIdx.x * 256 + threadIdx.x;
  if (e < EE) {
    int dst = ei[EE + e];
    int src = ei[e];
    int a9 = ea[2 * e] * 3 + ea[2 * e + 1];
    int sc = xcode[src];
    int pos = atomicAdd(&cursor[dst], 1);
    eslot[pos] = src | (a9 << 18) | (sc << 22);
  }
}

// ---------------- fused layer: packed-fp16 gather (BN affine inlined), fp16 MLP ----
// zin holds RAW z_{l-1}; per edge: p = relu_pk(z[src]*sc+sh); acc += p + comb.
// Packed-fp16 affine per edge replaces the k_bnfix streaming pass (r13/r14's 16
// us/layer) at ~8 extra pk-ops/edge-lane. x2 edge unroll (x4 was neutral-worse, r14).
// Block = 4 waves, 32 nodes, 16-lane sub-group per node.
// LDS: 16.9 KB union (AGG/T1/ldsZ). launch_bounds(256,5): cap above natural usage.
__global__ __launch_bounds__(256, 5) void k_layer(
    const ushort* __restrict__ zin, ushort* __restrict__ zout,
    const int* __restrict__ xcode, const ushort* __restrict__ tabh,
    const float* __restrict__ bnscale, const float* __restrict__ bnshift,
    const int* __restrict__ rowptr, const int* __restrict__ eslot,
    const ushort* __restrict__ w1s, const ushort* __restrict__ w2s,
    const float* __restrict__ b1, const float* __restrict__ b2,
    float* __restrict__ stats, int layer) {
  __shared__ __align__(16) ushort BUF[32 * 264];  // 16,896 B union
  ushort* AGG = BUF;   // 32 x 136 view (gather out / stage-1 in)
  ushort* T1 = BUF;    // 32 x 264 view (stage-1 out / stage-2 in)
  ushort* ldsZ = BUF;  // 32 x 136 view (stage-2 out / store staging)
  const int tid = threadIdx.x;
  const int w = tid >> 6, lane = tid & 63;
  const int ln16 = lane & 15, sub = lane >> 4;
  const int row0 = blockIdx.x * 32;

  // ---- gather phase: packed fp16, BN affine inlined ----
  const uint4* combH = (const uint4*)(tabh + (size_t)layer * 1152);
  const uint4* atomH = (const uint4*)(tabh + 6400);
  const uint4* selfH = (const uint4*)(tabh + 5760 + layer * 128);
  const uint4* h4 = (const uint4*)zin;
  f16x8 sf = ld8h(selfH, ln16);
  f16x8 scv = {}, shv = {};
  if (layer > 0) {
    const float* sp = bnscale + (layer - 1) * 128 + ln16 * 8;
    const float* hp = bnshift + (layer - 1) * 128 + ln16 * 8;
#pragma unroll
    for (int j = 0; j < 8; ++j) {
      scv[j] = (f16_t)sp[j];
      shv[j] = (f16_t)hp[j];
    }
  }

#pragma unroll
  for (int grp = 0; grp < 2; ++grp) {
    const int n = row0 + w * 8 + grp * 4 + sub;
    const int s = rowptr[n], e = rowptr[n + 1];
    f16x8 acc;
    if (layer == 0) {
      acc = ld8h(atomH, xcode[n] * 16 + ln16) + sf;
    } else {
      acc = bnrelu8(ld8h(h4, (size_t)n * 16 + ln16), scv, shv) + sf;
    }
    for (int base = s; base < e; base += 16) {
      int m = e - base;
      if (m > 16) m = 16;
      int slot = (ln16 < m) ? eslot[base + ln16] : 0;
      int j = 0;
      for (; j + 2 <= m; j += 2) {
        int sl0 = __shfl(slot, sub * 16 + j, 64);
        int sl1 = __shfl(slot, sub * 16 + j + 1, 64);
        f16x8 p0, p1;
        if (layer == 0) {
          p0 = ld8h(atomH, ((sl0 >> 22) & 15) * 16 + ln16);
          p1 = ld8h(atomH, ((sl1 >> 22) & 15) * 16 + ln16);
        } else {
          p0 = bnrelu8(ld8h(h4, (size_t)(sl0 & 0x3FFFF) * 16 + ln16), scv, shv);
          p1 = bnrelu8(ld8h(h4, (size_t)(sl1 & 0x3FFFF) * 16 + ln16), scv, shv);
        }
        f16x8 c0 = ld8h(combH, ((sl0 >> 18) & 15) * 16 + ln16);
        f16x8 c1 = ld8h(combH, ((sl1 >> 18) & 15) * 16 + ln16);
        acc += p0 + c0;
        acc += p1 + c1;
      }
      if (j < m) {
        int sl = __shfl(slot, sub * 16 + j, 64);
        f16x8 p0;
        if (layer == 0) {
          p0 = ld8h(atomH, ((sl >> 22) & 15) * 16 + ln16);
        } else {
          p0 = bnrelu8(ld8h(h4, (size_t)(sl & 0x3FFFF) * 16 + ln16), scv, shv);
        }
        f16x8 c0 = ld8h(combH, ((sl >> 18) & 15) * 16 + ln16);
        acc += p0 + c0;
      }
    }
    *(uint4*)&AGG[(w * 8 + grp * 4 + sub) * 136 + ln16 * 8] =
        __builtin_bit_cast(uint4, acc);
  }
  __syncthreads();

  // ---- MLP stage 1: acc = AGG @ W1, M=32, fp16 ----
  const int lm = ln16, q = sub;
  f32x4 acc[2][4] = {};
  const ushort* w1b = w1s + layer * 64 * 512;
#pragma unroll
  for (int kt = 0; kt < 4; ++kt) {
    f16x8 af[2], bf[4];
#pragma unroll
    for (int mt = 0; mt < 2; ++mt) {
      const ushort* p = AGG + (mt * 16 + lm) * 136 + kt * 32 + q * 8;
      af[mt] = __builtin_bit_cast(f16x8, *(const ushort8*)p);
    }
#pragma unroll
    for (int nt = 0; nt < 4; ++nt) {
      const ushort* p = w1b + (kt * 16 + w * 4 + nt) * 512 + lane * 8;
      bf[nt] = __builtin_bit_cast(f16x8, *(const ushort8*)p);
    }
#pragma unroll
    for (int mt = 0; mt < 2; ++mt)
#pragma unroll
      for (int nt = 0; nt < 4; ++nt)
        acc[mt][nt] = __builtin_amdgcn_mfma_f32_16x16x32_f16(af[mt], bf[nt], acc[mt][nt], 0, 0, 0);
  }
  __syncthreads();  // AGG dead; T1 may now overwrite the union buffer
#pragma unroll
  for (int nt = 0; nt < 4; ++nt) {
    int n = w * 64 + nt * 16 + lm;
    float bias = b1[layer * 256 + n];
#pragma unroll
    for (int mt = 0; mt < 2; ++mt)
#pragma unroll
      for (int r = 0; r < 4; ++r) {
        float v = fmaxf(acc[mt][nt][r] + bias, 0.0f);
        T1[(mt * 16 + q * 4 + r) * 264 + n] = f2h(v);
      }
  }
  __syncthreads();

  // ---- MLP stage 2: z = T1 @ W2 + b2, + BN stats epilogue ----
  f32x4 acc2[2][2] = {};
  const ushort* w2b = w2s + layer * 64 * 512;
#pragma unroll
  for (int kt = 0; kt < 8; ++kt) {
    f16x8 af[2], bf[2];
#pragma unroll
    for (int mt = 0; mt < 2; ++mt) {
      const ushort* p = T1 + (mt * 16 + lm) * 264 + kt * 32 + q * 8;
      af[mt] = __builtin_bit_cast(f16x8, *(const ushort8*)p);
    }
#pragma unroll
    for (int nt = 0; nt < 2; ++nt) {
      const ushort* p = w2b + (kt * 8 + w * 2 + nt) * 512 + lane * 8;
      bf[nt] = __builtin_bit_cast(f16x8, *(const ushort8*)p);
    }
#pragma unroll
    for (int mt = 0; mt < 2; ++mt)
#pragma unroll
      for (int nt = 0; nt < 2; ++nt)
        acc2[mt][nt] = __builtin_amdgcn_mfma_f32_16x16x32_f16(af[mt], bf[nt], acc2[mt][nt], 0, 0, 0);
  }
  __syncthreads();  // T1 dead; ldsZ may now overwrite the union buffer
  float ssum[2], ssq[2];
#pragma unroll
  for (int nt = 0; nt < 2; ++nt) {
    int n = w * 32 + nt * 16 + lm;
    float bias = b2[layer * 128 + n];
    ssum[nt] = 0.f;
    ssq[nt] = 0.f;
#pragma unroll
    for (int mt = 0; mt < 2; ++mt)
#pragma unroll
      for (int r = 0; r < 4; ++r) {
        float v = acc2[mt][nt][r] + bias;
        ldsZ[(mt * 16 + q * 4 + r) * 136 + n] = f2h(v);
        ssum[nt] += v;
        ssq[nt] += v * v;
      }
    ssum[nt] += __shfl_xor(ssum[nt], 16, 64);
    ssum[nt] += __shfl_xor(ssum[nt], 32, 64);
    ssq[nt] += __shfl_xor(ssq[nt], 16, 64);
    ssq[nt] += __shfl_xor(ssq[nt], 32, 64);
  }
  if (lane < 16) {
    int cp = blockIdx.x & 15;
    float* sb = stats + (size_t)(layer * 16 + cp) * 256;
#pragma unroll
    for (int nt = 0; nt < 2; ++nt) {
      int col = w * 32 + nt * 16 + lane;
      atomicAdd(&sb[col], ssum[nt]);
      atomicAdd(&sb[128 + col], ssq[nt]);
    }
  }
  __syncthreads();
  uint* zo = (uint*)zout;
  for (int i = tid; i < 32 * 64; i += 256) {
    int row = i >> 6, cpx = i & 63;
    uint v = *(const uint*)&ldsZ[row * 136 + cpx * 2];
    zo[(size_t)(row0 + row) * 64 + cpx] = v;
  }
}

__global__ void k_bnparam(const float* __restrict__ stats, const float* __restrict__ gamma,
                          const float* __restrict__ beta, float* __restrict__ bnscale,
                          float* __restrict__ bnshift, int layer) {
  int c = threadIdx.x;
  float s = 0.f, qv = 0.f;
  for (int cp = 0; cp < 16; ++cp) {
    const float* sb = stats + (size_t)(layer * 16 + cp) * 256;
    s += sb[c];
    qv += sb[128 + c];
  }
  float mu = s * (1.0f / NN);
  float var = qv * (1.0f / NN) - mu * mu;
  float sc = gamma[layer * 128 + c] * rsqrtf(var + 1e-5f);
  bnscale[layer * 128 + c] = sc;
  bnshift[layer * 128 + c] = beta[layer * 128 + c] - mu * sc;
}

// ---------------- pooling with segmented running sum (batch sorted) ----------------
__global__ __launch_bounds__(256) void k_pool(const ushort* __restrict__ z,
                                              const float* __restrict__ bnscale,
                                              const float* __restrict__ bnshift,
                                              const int* __restrict__ batch,
                                              const float* __restrict__ Wp,
                                              float* __restrict__ out) {
  const int tid = threadIdx.x;
  const int w = tid >> 6, lane = tid & 63;
  const int nb = blockIdx.x * 64 + w * 16;
  float2 wp = ((const float2*)Wp)[lane];
  float2 scv = ((const float2*)(bnscale + 4 * 128))[lane];
  float2 shv = ((const float2*)(bnshift + 4 * 128))[lane];
  const uint* z32 = (const uint*)z;
  int bb = (lane < 16) ? batch[nb + lane] : 0;
  int curb = __shfl(bb, 0);
  float run = 0.f;
#pragma unroll
  for (int i = 0; i < 16; ++i) {
    int b = __shfl(bb, i);
    uint u = z32[(size_t)(nb + i) * 64 + lane];
    float dot = fmaf(hlo(u), scv.x, shv.x) * wp.x + fmaf(hhi(u), scv.y, shv.y) * wp.y;
#pragma unroll
    for (int off = 32; off > 0; off >>= 1) dot += __shfl_xor(dot, off, 64);
    if (b != curb) {
      if (lane == 0) atomicAdd(&out[curb], run);
      run = 0.f;
      curb = b;
    }
    run += dot;
  }
  if (lane == 0) atomicAdd(&out[curb], run);
}

extern "C" void kernel_launch(void* const* d_in, const int* in_sizes, int n_in,
                              void* d_out, int out_size, void* d_ws, size_t ws_size,
                              hipStream_t stream) {
  (void)in_sizes; (void)n_in; (void)out_size; (void)ws_size;
  const int* xidx = (const int*)d_in[0];
  const int* eidx = (const int*)d_in[1];
  const int* eattr = (const int*)d_in[2];
  const int* batch = (const int*)d_in[3];
  const float* at1 = (const float*)d_in[4];
  const float* at2 = (const float*)d_in[5];
  const float* ee1 = (const float*)d_in[6];
  const float* ee2 = (const float*)d_in[7];
  const float* W1 = (const float*)d_in[8];
  const float* b1 = (const float*)d_in[9];
  const float* W2 = (const float*)d_in[10];
  const float* b2 = (const float*)d_in[11];
  const float* gamma = (const float*)d_in[12];
  const float* beta = (const float*)d_in[13];
  const float* Wp = (const float*)d_in[14];
  const float* bp = (const float*)d_in[15];
  float* out = (float*)d_out;

  char* ws = (char*)d_ws;
  size_t off = 0;
  auto alloc = [&](size_t bytes) -> void* {
    void* p = ws + off;
    off = (off + bytes + 255) & ~(size_t)255;
    return p;
  };
  ushort* bufA = (ushort*)alloc((size_t)NN * 128 * 2);
  ushort* bufB = (ushort*)alloc((size_t)NN * 128 * 2);
  ushort* w1s = (ushort*)alloc(320 * 512 * 2);
  ushort* w2s = (ushort*)alloc(320 * 512 * 2);
  int* rowptr = (int*)alloc((NN + 1) * 4);
  int* cursor = (int*)alloc((size_t)NN * 4);
  int* eslot = (int*)alloc((size_t)EE * 4);
  int* bsums = (int*)alloc(1024 * 4);
  ushort* tabh = (ushort*)alloc(7552 * 2);
  int* xcode = (int*)alloc((size_t)NN * 4);
  float* stats = (float*)alloc((size_t)LL * 16 * 256 * 4);
  float* bnscale = (float*)alloc(LL * 128 * 4);
  float* bnshift = (float*)alloc(LL * 128 * 4);

  hipMemsetAsync(cursor, 0, (size_t)NN * 4, stream);
  hipMemsetAsync(stats, 0, (size_t)LL * 16 * 256 * 4, stream);
  k_setup<<<SCAN_NB, 256, 0, stream>>>(W1, W2, w1s, w2s, ee1, ee2, at1, at2, tabh, xidx,
                                       xcode, out, bp);
  k_count<<<(EE + 255) / 256, 256, 0, stream>>>(eidx, cursor);
  k_scanA<<<SCAN_NB, 256, 0, stream>>>(cursor, rowptr, bsums);
  k_scanB<<<1, 1024, 0, stream>>>(bsums);
  k_scanC<<<SCAN_NB, 256, 0, stream>>>(rowptr, bsums);
  hipMemcpyAsync(cursor, rowptr, (size_t)NN * 4, hipMemcpyDeviceToDevice, stream);
  k_fill<<<(EE + 255) / 256, 256, 0, stream>>>(eidx, eattr, xcode, cursor, eslot);

  for (int l = 0; l < LL; ++l) {
    ushort* zo = (l & 1) ? bufB : bufA;
    const ushort* zi = (l & 1) ? bufA : bufB;  // raw z_{l-1}; unused for l==0
    k_layer<<<NN / 32, 256, 0, stream>>>((l == 0) ? bufA : zi, zo, xcode, tabh, bnscale,
                                         bnshift, rowptr, eslot, w1s, w2s, b1, b2,
                                         stats, l);
    k_bnparam<<<1, 128, 0, stream>>>(stats, gamma, beta, bnscale, bnshift, l);
  }
  k_pool<<<NN / 64, 256, 0, stream>>>(bufA, bnscale, bnshift, batch, Wp, out);
}